// Round 11
// baseline (272.030 us; speedup 1.0000x reference)
//
#include <hip/hip_runtime.h>
#include <cstdint>

#define N_NODES 50000
#define N_EDGES 800000
#define E_TOT   (N_EDGES + N_NODES)   // 850000 with self-loops
#define IN_CH   128
#define HEADS   8
#define CCH     32
#define HC      256                    // HEADS*CCH
#define OUTC    64

typedef unsigned short ushort_t;
typedef __attribute__((ext_vector_type(8))) short bf16x8;
typedef __attribute__((ext_vector_type(8))) unsigned short u16x8;
typedef __attribute__((ext_vector_type(4))) float f32x4;

// bf16 helpers (RNE rounding on pack)
static __device__ __forceinline__ unsigned short f2bf(float f) {
    unsigned u = __float_as_uint(f);
    u = u + 0x7fffu + ((u >> 16) & 1u);
    return (unsigned short)(u >> 16);
}
static __device__ __forceinline__ float bf2f(unsigned short h) {
    return __uint_as_float((unsigned)h << 16);
}
static __device__ __forceinline__ unsigned pack2(float lo, float hi) {
    return (unsigned)f2bf(lo) | ((unsigned)f2bf(hi) << 16);
}
static __device__ __forceinline__ float lrexp(float v) {
    v = v > 0.f ? v : 0.2f * v;        // LeakyReLU(0.2)
    return expf(v);
}
static __device__ __forceinline__ bf16x8 cvt8(float4 lo, float4 hi) {
    bf16x8 r;
    r[0] = (short)f2bf(lo.x); r[1] = (short)f2bf(lo.y);
    r[2] = (short)f2bf(lo.z); r[3] = (short)f2bf(lo.w);
    r[4] = (short)f2bf(hi.x); r[5] = (short)f2bf(hi.y);
    r[6] = (short)f2bf(hi.z); r[7] = (short)f2bf(hi.w);
    return r;
}

// ======================= CSR construction (per call) ========================
__global__ __launch_bounds__(256) void hist_kernel(
        const int* __restrict__ ei, int* __restrict__ deg) {
    int e = blockIdx.x * 256 + threadIdx.x;
    if (e >= E_TOT) return;
    int dv = (e < N_EDGES) ? ei[N_EDGES + e] : (e - N_EDGES);
    atomicAdd(&deg[dv], 1);
}

__global__ __launch_bounds__(1024) void scan1_kernel(
        const int* __restrict__ deg, int* __restrict__ inc, int* __restrict__ bsum) {
    __shared__ int sh[1024];
    const int tid = threadIdx.x;
    const int i = blockIdx.x * 1024 + tid;
    sh[tid] = (i < N_NODES) ? deg[i] : 0;
    __syncthreads();
    for (int o = 1; o < 1024; o <<= 1) {
        int t = (tid >= o) ? sh[tid - o] : 0;
        __syncthreads();
        sh[tid] += t;
        __syncthreads();
    }
    if (i < N_NODES) inc[i] = sh[tid];
    if (tid == 1023) bsum[blockIdx.x] = sh[1023];
}

#define NSCAN_BLOCKS ((N_NODES + 1023) / 1024)   // 49
// finalize with scan2 folded in: every block redundantly prefix-sums bsum[49]
__global__ __launch_bounds__(256) void finalize_kernel(
        const int* __restrict__ inc, const int* __restrict__ bsum,
        int* __restrict__ rowstart, int* __restrict__ cursor) {
    __shared__ int pref[NSCAN_BLOCKS];
    if (threadIdx.x == 0) {
        int acc = 0;
        #pragma unroll 7
        for (int k = 0; k < NSCAN_BLOCKS; ++k) { pref[k] = acc; acc += bsum[k]; }
    }
    __syncthreads();
    int i = blockIdx.x * 256 + threadIdx.x;
    if (i >= N_NODES) return;
    int v = inc[i] + pref[i >> 10];
    rowstart[i + 1] = v;
    if (i + 1 < N_NODES) cursor[i + 1] = v;
    if (i == 0) { rowstart[0] = 0; cursor[0] = 0; }
}

// scatter: col only
__global__ __launch_bounds__(256) void scatter_kernel(
        const int* __restrict__ ei, int* __restrict__ cursor, int* __restrict__ col) {
    int e = blockIdx.x * 256 + threadIdx.x;
    if (e >= E_TOT) return;
    int sv, dv;
    if (e < N_EDGES) { sv = ei[e]; dv = ei[N_EDGES + e]; }
    else             { sv = dv = e - N_EDGES; }
    int pos = atomicAdd(&cursor[dv], 1);
    col[pos] = sv;
}

// ========== Repack W1,W2 to bf16 fragment-ordered tables ====================
// MFMA tile nt covers output col(nt,c) = (nt>>1)*32 + 2*c + (nt&1), c=lane&15.
__global__ __launch_bounds__(256) void repack_w(
        const float* __restrict__ W1, const float* __restrict__ W2,
        ushort_t* __restrict__ W1f, ushort_t* __restrict__ W2f) {
    int t = blockIdx.x * 256 + threadIdx.x;
    if (t < 32768) {
        int j = t & 7, lane = (t >> 3) & 63, f = t >> 9;
        int nt = f >> 2, kk = f & 3;
        int k = kk * 32 + (lane >> 4) * 8 + j;
        int n = (nt >> 1) * 32 + 2 * (lane & 15) + (nt & 1);
        W1f[t] = f2bf(W1[k * HC + n]);
    } else if (t < 32768 + 16384) {
        int u = t - 32768;
        int j = u & 7, lane = (u >> 3) & 63, f = u >> 9;
        int nt = f >> 3, kk = f & 7;
        int k = kk * 32 + (lane >> 4) * 8 + j;
        int n = (nt >> 1) * 32 + 2 * (lane & 15) + (nt & 1);
        W2f[u] = f2bf(W2[k * OUTC + n]);
    }
}

// ====== Layer 1 MFMA GEMM + fused logits: h1b(bf16), al1, ar1 ===============
__global__ __launch_bounds__(256) void gemm1_mfma(
        const float* __restrict__ x, const ushort_t* __restrict__ W1f,
        const float* __restrict__ a_src, const float* __restrict__ a_dst,
        ushort_t* __restrict__ h1b, float* __restrict__ al, float* __restrict__ ar) {
    const int lane = threadIdx.x & 63;
    const int wv   = threadIdx.x >> 6;
    const int base = blockIdx.x * 64 + wv * 16;
    if (base >= N_NODES) return;
    const int am = base + (lane & 15);
    const int rm = am < N_NODES ? am : N_NODES - 1;

    bf16x8 a[4];
    const float* xr = &x[(size_t)rm * IN_CH + (lane >> 4) * 8];
    #pragma unroll
    for (int kk = 0; kk < 4; ++kk) {
        float4 lo = *(const float4*)&xr[kk * 32];
        float4 hi = *(const float4*)&xr[kk * 32 + 4];
        a[kk] = cvt8(lo, hi);
    }

    f32x4 acc[16];
    #pragma unroll
    for (int nt = 0; nt < 16; ++nt) acc[nt] = (f32x4){0.f, 0.f, 0.f, 0.f};

    const bf16x8* bp = (const bf16x8*)W1f;
    #pragma unroll
    for (int nt = 0; nt < 16; ++nt) {
        #pragma unroll
        for (int kk = 0; kk < 4; ++kk)
            acc[nt] = __builtin_amdgcn_mfma_f32_16x16x32_bf16(
                a[kk], bp[(nt * 4 + kk) * 64 + lane], acc[nt], 0, 0, 0);
    }

    #pragma unroll
    for (int r = 0; r < 4; ++r) {
        int node = base + (lane >> 4) * 4 + r;
        if (node < N_NODES) {
            unsigned* op = (unsigned*)&h1b[(size_t)node * HC + 2 * (lane & 15)];
            #pragma unroll
            for (int t = 0; t < 8; ++t)
                op[t * 16] = pack2(acc[2 * t][r], acc[2 * t + 1][r]);
        }
    }

    float asv[16], adv[16];
    #pragma unroll
    for (int nt = 0; nt < 16; ++nt) {
        int n = (nt >> 1) * 32 + 2 * (lane & 15) + (nt & 1);
        asv[nt] = a_src[n];
        adv[nt] = a_dst[n];
    }
    #pragma unroll
    for (int h = 0; h < HEADS; ++h) {
        #pragma unroll
        for (int r = 0; r < 4; ++r) {
            float s = acc[2 * h][r] * asv[2 * h] + acc[2 * h + 1][r] * asv[2 * h + 1];
            float d = acc[2 * h][r] * adv[2 * h] + acc[2 * h + 1][r] * adv[2 * h + 1];
            s += __shfl_xor(s, 1, 64); s += __shfl_xor(s, 2, 64);
            s += __shfl_xor(s, 4, 64); s += __shfl_xor(s, 8, 64);
            d += __shfl_xor(d, 1, 64); d += __shfl_xor(d, 2, 64);
            d += __shfl_xor(d, 4, 64); d += __shfl_xor(d, 8, 64);
            int node = base + (lane >> 4) * 4 + r;
            if ((lane & 15) == 0 && node < N_NODES) {
                al[node * HEADS + h] = s;
                ar[node * HEADS + h] = d;
            }
        }
    }
}

// ===== Layer 1 exp+denominator precompute (CSR-ordered, no row[] needed) ====
// wave per dst row; 8 lanes/edge (lane&7 = head). Writes expv bf16 and inv1.
__global__ __launch_bounds__(256) void alpha1_csr(
        const int* __restrict__ rowstart, const int* __restrict__ col,
        const float* __restrict__ al, const float* __restrict__ ar,
        ushort_t* __restrict__ expv, float* __restrict__ inv1) {
    const int lane = threadIdx.x & 63;
    const int d = blockIdx.x * 4 + (threadIdx.x >> 6);
    if (d >= N_NODES) return;
    const int beg = rowstart[d], end = rowstart[d + 1];
    const int h8 = lane & 7;
    const float ar_h8 = ar[d * HEADS + h8];
    float denom = 0.f;
    for (int i = beg + (lane >> 3); i < end; i += 8) {
        float e = lrexp(al[col[i] * HEADS + h8] + ar_h8);
        expv[(size_t)i * 8 + h8] = f2bf(e);
        denom += e;
    }
    denom += __shfl_xor(denom, 8, 64);
    denom += __shfl_xor(denom, 16, 64);
    denom += __shfl_xor(denom, 32, 64);          // lane holds denom of head lane&7
    if (lane < 8) inv1[d * HEADS + lane] = 1.f / (denom + 1e-16f);
}

// ===== Layer 1 aggregation: single-pass gather + bias + ELU -> bf16 =========
__global__ __launch_bounds__(256) void aggr1_csr(
        const int* __restrict__ rowstart, const int* __restrict__ col,
        const ushort_t* __restrict__ expv, const float* __restrict__ inv1,
        const unsigned short* __restrict__ h1b, const float* __restrict__ b1,
        unsigned short* __restrict__ out1b) {
    const int lane = threadIdx.x & 63;
    const int d = blockIdx.x * 4 + (threadIdx.x >> 6);
    if (d >= N_NODES) return;
    const int beg = rowstart[d], end = rowstart[d + 1];

    const int half = lane >> 5;                  // 0: even edges, 1: odd edges
    const int L    = lane & 31;                  // channel block: c = L*8 .. L*8+7
    const int hh   = L >> 2;                     // head of these 8 channels
    const float inv = inv1[d * HEADS + hh];

    // single pass: 2 edges per gather instruction, 4 pairs in flight
    float acc8[8] = {0.f,0.f,0.f,0.f,0.f,0.f,0.f,0.f};
    int i = beg;
    for (; i + 7 < end; i += 8) {
        int sv[4]; float wv[4];
        #pragma unroll
        for (int q = 0; q < 4; ++q) sv[q] = col[i + 2 * q + half];
        #pragma unroll
        for (int q = 0; q < 4; ++q)
            wv[q] = bf2f(expv[(size_t)(i + 2 * q + half) * 8 + hh]) * inv;
        #pragma unroll
        for (int q = 0; q < 4; ++q) {
            const u16x8 v = *(const u16x8*)&h1b[(size_t)sv[q] * HC + L * 8];
            #pragma unroll
            for (int j = 0; j < 8; ++j) acc8[j] += wv[q] * bf2f(v[j]);
        }
    }
    for (; i < end; i += 2) {
        const int e = i + half;
        const bool ok = e < end;
        const int s = col[ok ? e : end - 1];
        const float w = ok ? bf2f(expv[(size_t)e * 8 + hh]) * inv : 0.f;
        const u16x8 v = *(const u16x8*)&h1b[(size_t)s * HC + L * 8];
        #pragma unroll
        for (int j = 0; j < 8; ++j) acc8[j] += w * bf2f(v[j]);
    }
    // combine halves
    #pragma unroll
    for (int j = 0; j < 8; ++j) acc8[j] += __shfl_xor(acc8[j], 32, 64);

    if (half == 0) {
        const float4 b0 = *(const float4*)&b1[L * 8];
        const float4 b4 = *(const float4*)&b1[L * 8 + 4];
        float bb[8] = {b0.x, b0.y, b0.z, b0.w, b4.x, b4.y, b4.z, b4.w};
        u16x8 ov;
        #pragma unroll
        for (int j = 0; j < 8; ++j) {
            float v = acc8[j] + bb[j];
            v = v > 0.f ? v : expf(v) - 1.f;
            ov[j] = f2bf(v);
        }
        *(u16x8*)&out1b[(size_t)d * HC + L * 8] = ov;
    }
}

// ====== Layer 2 MFMA GEMM + fused logits: h2b(bf16), al2, ar2 ===============
__global__ __launch_bounds__(256) void gemm2_mfma(
        const ushort_t* __restrict__ hinb, const ushort_t* __restrict__ W2f,
        const float* __restrict__ a_src, const float* __restrict__ a_dst,
        ushort_t* __restrict__ h2b, float* __restrict__ al, float* __restrict__ ar) {
    const int lane = threadIdx.x & 63;
    const int wv   = threadIdx.x >> 6;
    const int base = blockIdx.x * 64 + wv * 16;
    if (base >= N_NODES) return;
    const int am = base + (lane & 15);
    const int rm = am < N_NODES ? am : N_NODES - 1;

    bf16x8 a[8];
    const bf16x8* ap = (const bf16x8*)&hinb[(size_t)rm * HC];
    #pragma unroll
    for (int kk = 0; kk < 8; ++kk)
        a[kk] = ap[kk * 4 + (lane >> 4)];

    f32x4 acc[4];
    #pragma unroll
    for (int nt = 0; nt < 4; ++nt) acc[nt] = (f32x4){0.f, 0.f, 0.f, 0.f};

    const bf16x8* bp = (const bf16x8*)W2f;
    #pragma unroll
    for (int nt = 0; nt < 4; ++nt) {
        #pragma unroll
        for (int kk = 0; kk < 8; ++kk)
            acc[nt] = __builtin_amdgcn_mfma_f32_16x16x32_bf16(
                a[kk], bp[(nt * 8 + kk) * 64 + lane], acc[nt], 0, 0, 0);
    }

    #pragma unroll
    for (int r = 0; r < 4; ++r) {
        int node = base + (lane >> 4) * 4 + r;
        if (node < N_NODES) {
            unsigned* op = (unsigned*)&h2b[(size_t)node * OUTC + 2 * (lane & 15)];
            #pragma unroll
            for (int t = 0; t < 2; ++t)
                op[t * 16] = pack2(acc[2 * t][r], acc[2 * t + 1][r]);
        }
    }

    float asv[4], adv[4];
    #pragma unroll
    for (int nt = 0; nt < 4; ++nt) {
        int n = (nt >> 1) * 32 + 2 * (lane & 15) + (nt & 1);
        asv[nt] = a_src[n];
        adv[nt] = a_dst[n];
    }
    #pragma unroll
    for (int r = 0; r < 4; ++r) {
        float s = 0.f, d = 0.f;
        #pragma unroll
        for (int nt = 0; nt < 4; ++nt) {
            s += acc[nt][r] * asv[nt];
            d += acc[nt][r] * adv[nt];
        }
        s += __shfl_xor(s, 1, 64); s += __shfl_xor(s, 2, 64);
        s += __shfl_xor(s, 4, 64); s += __shfl_xor(s, 8, 64);
        d += __shfl_xor(d, 1, 64); d += __shfl_xor(d, 2, 64);
        d += __shfl_xor(d, 4, 64); d += __shfl_xor(d, 8, 64);
        int node = base + (lane >> 4) * 4 + r;
        if ((lane & 15) == 0 && node < N_NODES) { al[node] = s; ar[node] = d; }
    }
}

// ===== Layer 2 exp+denominator precompute (CSR-ordered) =====================
__global__ __launch_bounds__(256) void alpha2_csr(
        const int* __restrict__ rowstart, const int* __restrict__ col,
        const float* __restrict__ al, const float* __restrict__ ar,
        float* __restrict__ expv, float* __restrict__ inv2) {
    const int lane = threadIdx.x & 63;
    const int d = blockIdx.x * 4 + (threadIdx.x >> 6);
    if (d >= N_NODES) return;
    const int beg = rowstart[d], end = rowstart[d + 1];
    const float ard = ar[d];
    float denom = 0.f;
    for (int i = beg + lane; i < end; i += 64) {
        float e = lrexp(al[col[i]] + ard);
        expv[i] = e;
        denom += e;
    }
    #pragma unroll
    for (int o = 1; o < 64; o <<= 1) denom += __shfl_xor(denom, o, 64);
    if (lane == 0) inv2[d] = 1.f / (denom + 1e-16f);
}

// ===== Layer 2 aggregation: single-pass gather + bias (fp32 out) ============
__global__ __launch_bounds__(256) void aggr2_csr(
        const int* __restrict__ rowstart, const int* __restrict__ col,
        const float* __restrict__ expv, const float* __restrict__ inv2,
        const unsigned short* __restrict__ h2b, const float* __restrict__ b2,
        float* __restrict__ out) {
    const int lane = threadIdx.x & 63;
    const int d = blockIdx.x * 4 + (threadIdx.x >> 6);
    if (d >= N_NODES) return;
    const int beg = rowstart[d], end = rowstart[d + 1];
    const float inv = inv2[d];

    const int g = lane >> 4;      // edge slot 0..3
    const int L = lane & 15;      // channel block: c = L*4 .. L*4+3

    float4 acc = {0.f, 0.f, 0.f, 0.f};
    int i = beg;
    for (; i + 7 < end; i += 8) {
        const int s0 = col[i + g], s1 = col[i + 4 + g];
        const float w0 = expv[i + g] * inv, w1 = expv[i + 4 + g] * inv;
        const ushort4 v0 = *(const ushort4*)&h2b[(size_t)s0 * OUTC + L * 4];
        const ushort4 v1 = *(const ushort4*)&h2b[(size_t)s1 * OUTC + L * 4];
        acc.x += w0 * bf2f(v0.x) + w1 * bf2f(v1.x);
        acc.y += w0 * bf2f(v0.y) + w1 * bf2f(v1.y);
        acc.z += w0 * bf2f(v0.z) + w1 * bf2f(v1.z);
        acc.w += w0 * bf2f(v0.w) + w1 * bf2f(v1.w);
    }
    for (; i < end; i += 4) {
        const int e = i + g;
        const bool ok = e < end;
        const int s = col[ok ? e : end - 1];
        const float w = ok ? expv[e] * inv : 0.f;
        const ushort4 v = *(const ushort4*)&h2b[(size_t)s * OUTC + L * 4];
        acc.x += w * bf2f(v.x); acc.y += w * bf2f(v.y);
        acc.z += w * bf2f(v.z); acc.w += w * bf2f(v.w);
    }
    // combine the 4 edge slots
    #pragma unroll
    for (int o = 16; o < 64; o <<= 1) {
        acc.x += __shfl_xor(acc.x, o, 64);
        acc.y += __shfl_xor(acc.y, o, 64);
        acc.z += __shfl_xor(acc.z, o, 64);
        acc.w += __shfl_xor(acc.w, o, 64);
    }
    if (g == 0) {
        const float4 bb = *(const float4*)&b2[L * 4];
        float4 ov = { acc.x + bb.x, acc.y + bb.y, acc.z + bb.z, acc.w + bb.w };
        *(float4*)&out[(size_t)d * OUTC + L * 4] = ov;
    }
}

extern "C" void kernel_launch(void* const* d_in, const int* in_sizes, int n_in,
                              void* d_out, int out_size, void* d_ws, size_t ws_size,
                              hipStream_t stream) {
    const float* x      = (const float*)d_in[0];
    const int*   ei     = (const int*)  d_in[1];
    const float* W1     = (const float*)d_in[2];
    const float* a_src1 = (const float*)d_in[3];
    const float* a_dst1 = (const float*)d_in[4];
    const float* b1     = (const float*)d_in[5];
    const float* W2     = (const float*)d_in[6];
    const float* a_src2 = (const float*)d_in[7];
    const float* a_dst2 = (const float*)d_in[8];
    const float* b2     = (const float*)d_in[9];
    float* out = (float*)d_out;

    // ---- workspace layout ----
    char* p = (char*)d_ws;
    ushort_t* h1b   = (ushort_t*)p; p += (size_t)N_NODES * HC * 2;   // 25.6 MB
    ushort_t* out1b = (ushort_t*)p; p += (size_t)N_NODES * HC * 2;   // 25.6 MB
    ushort_t* h2b   = (ushort_t*)p; p += (size_t)N_NODES * OUTC * 2; // 6.4 MB
    ushort_t* expv1 = (ushort_t*)p; p += (size_t)E_TOT * 8 * 2;      // 13.6 MB
    float* expv2 = (float*)p; p += (size_t)E_TOT * sizeof(float);    // 3.4 MB
    ushort_t* W1f  = (ushort_t*)p; p += 32768 * 2;                   // 64 KB
    ushort_t* W2f  = (ushort_t*)p; p += 16384 * 2;                   // 32 KB
    float* al1  = (float*)p;  p += (size_t)N_NODES * HEADS * sizeof(float);
    float* ar1  = (float*)p;  p += (size_t)N_NODES * HEADS * sizeof(float);
    float* inv1 = (float*)p;  p += (size_t)N_NODES * HEADS * sizeof(float);
    float* al2  = (float*)p;  p += (size_t)N_NODES * sizeof(float);
    float* ar2  = (float*)p;  p += (size_t)N_NODES * sizeof(float);
    float* inv2 = (float*)p;  p += (size_t)N_NODES * sizeof(float);
    int* deg      = (int*)p;  p += (size_t)N_NODES * sizeof(int);
    int* inc      = (int*)p;  p += (size_t)N_NODES * sizeof(int);
    int* bsum     = (int*)p;  p += (size_t)NSCAN_BLOCKS * sizeof(int);
    int* rowstart = (int*)p;  p += (size_t)(N_NODES + 1) * sizeof(int);
    int* cursor   = (int*)p;  p += (size_t)N_NODES * sizeof(int);
    int* col      = (int*)p;  p += (size_t)E_TOT * sizeof(int);

    // ---- CSR build + weight repack ----
    hipMemsetAsync(deg, 0, (size_t)N_NODES * sizeof(int), stream);
    repack_w       <<<192, 256, 0, stream>>>(W1, W2, W1f, W2f);
    hist_kernel    <<<(E_TOT + 255)/256, 256, 0, stream>>>(ei, deg);
    scan1_kernel   <<<NSCAN_BLOCKS, 1024, 0, stream>>>(deg, inc, bsum);
    finalize_kernel<<<(N_NODES + 255)/256, 256, 0, stream>>>(inc, bsum, rowstart, cursor);
    scatter_kernel <<<(E_TOT + 255)/256, 256, 0, stream>>>(ei, cursor, col);

    // ---- layer 1 ----
    gemm1_mfma <<<(N_NODES + 63)/64, 256, 0, stream>>>(x, W1f, a_src1, a_dst1, h1b, al1, ar1);
    alpha1_csr <<<(N_NODES + 3)/4, 256, 0, stream>>>(rowstart, col, al1, ar1, expv1, inv1);
    aggr1_csr  <<<(N_NODES + 3)/4, 256, 0, stream>>>(rowstart, col, expv1, inv1, h1b, b1, out1b);

    // ---- layer 2 ----
    gemm2_mfma <<<(N_NODES + 63)/64, 256, 0, stream>>>(out1b, W2f, a_src2, a_dst2, h2b, al2, ar2);
    alpha2_csr <<<(N_NODES + 3)/4, 256, 0, stream>>>(rowstart, col, al2, ar2, expv2, inv2);
    aggr2_csr  <<<(N_NODES + 3)/4, 256, 0, stream>>>(rowstart, col, expv2, inv2, h2b, b2, out);
}

// Round 12
// 254.122 us; speedup vs baseline: 1.0705x; 1.0705x over previous
//
#include <hip/hip_runtime.h>
#include <cstdint>

#define N_NODES 50000
#define N_EDGES 800000
#define E_TOT   (N_EDGES + N_NODES)   // 850000 with self-loops
#define IN_CH   128
#define HEADS   8
#define CCH     32
#define HC      256                    // HEADS*CCH
#define OUTC    64

typedef unsigned short ushort_t;
typedef __attribute__((ext_vector_type(8))) short bf16x8;
typedef __attribute__((ext_vector_type(8))) unsigned short u16x8;
typedef __attribute__((ext_vector_type(4))) float f32x4;

// bf16 helpers (RNE rounding on pack)
static __device__ __forceinline__ unsigned short f2bf(float f) {
    unsigned u = __float_as_uint(f);
    u = u + 0x7fffu + ((u >> 16) & 1u);
    return (unsigned short)(u >> 16);
}
static __device__ __forceinline__ float bf2f(unsigned short h) {
    return __uint_as_float((unsigned)h << 16);
}
static __device__ __forceinline__ unsigned pack2(float lo, float hi) {
    return (unsigned)f2bf(lo) | ((unsigned)f2bf(hi) << 16);
}
static __device__ __forceinline__ float lrexp(float v) {
    v = v > 0.f ? v : 0.2f * v;        // LeakyReLU(0.2)
    return expf(v);
}
static __device__ __forceinline__ bf16x8 cvt8(float4 lo, float4 hi) {
    bf16x8 r;
    r[0] = (short)f2bf(lo.x); r[1] = (short)f2bf(lo.y);
    r[2] = (short)f2bf(lo.z); r[3] = (short)f2bf(lo.w);
    r[4] = (short)f2bf(hi.x); r[5] = (short)f2bf(hi.y);
    r[6] = (short)f2bf(hi.z); r[7] = (short)f2bf(hi.w);
    return r;
}

// ===== prep: weight repack (first blocks) + degree histogram (all blocks) ====
// MFMA tile nt covers output col(nt,c) = (nt>>1)*32 + 2*c + (nt&1), c=lane&15.
__global__ __launch_bounds__(256) void prep_kernel(
        const int* __restrict__ ei, int* __restrict__ deg,
        const float* __restrict__ W1, const float* __restrict__ W2,
        ushort_t* __restrict__ W1f, ushort_t* __restrict__ W2f) {
    int t = blockIdx.x * 256 + threadIdx.x;
    if (t < 32768) {
        int j = t & 7, lane = (t >> 3) & 63, f = t >> 9;
        int nt = f >> 2, kk = f & 3;
        int k = kk * 32 + (lane >> 4) * 8 + j;
        int n = (nt >> 1) * 32 + 2 * (lane & 15) + (nt & 1);
        W1f[t] = f2bf(W1[k * HC + n]);
    } else if (t < 32768 + 16384) {
        int u = t - 32768;
        int j = u & 7, lane = (u >> 3) & 63, f = u >> 9;
        int nt = f >> 3, kk = f & 7;
        int k = kk * 32 + (lane >> 4) * 8 + j;
        int n = (nt >> 1) * 32 + 2 * (lane & 15) + (nt & 1);
        W2f[u] = f2bf(W2[k * OUTC + n]);
    }
    if (t < E_TOT) {
        int dv = (t < N_EDGES) ? ei[N_EDGES + t] : (t - N_EDGES);
        atomicAdd(&deg[dv], 1);
    }
}

__global__ __launch_bounds__(1024) void scan1_kernel(
        const int* __restrict__ deg, int* __restrict__ inc, int* __restrict__ bsum) {
    __shared__ int sh[1024];
    const int tid = threadIdx.x;
    const int i = blockIdx.x * 1024 + tid;
    sh[tid] = (i < N_NODES) ? deg[i] : 0;
    __syncthreads();
    for (int o = 1; o < 1024; o <<= 1) {
        int t = (tid >= o) ? sh[tid - o] : 0;
        __syncthreads();
        sh[tid] += t;
        __syncthreads();
    }
    if (i < N_NODES) inc[i] = sh[tid];
    if (tid == 1023) bsum[blockIdx.x] = sh[1023];
}

#define NSCAN_BLOCKS ((N_NODES + 1023) / 1024)   // 49
// finalize with scan2 folded in: every block redundantly prefix-sums bsum[49]
__global__ __launch_bounds__(256) void finalize_kernel(
        const int* __restrict__ inc, const int* __restrict__ bsum,
        int* __restrict__ rowstart, int* __restrict__ cursor) {
    __shared__ int pref[NSCAN_BLOCKS];
    if (threadIdx.x == 0) {
        int acc = 0;
        #pragma unroll 7
        for (int k = 0; k < NSCAN_BLOCKS; ++k) { pref[k] = acc; acc += bsum[k]; }
    }
    __syncthreads();
    int i = blockIdx.x * 256 + threadIdx.x;
    if (i >= N_NODES) return;
    int v = inc[i] + pref[i >> 10];
    rowstart[i + 1] = v;
    if (i + 1 < N_NODES) cursor[i + 1] = v;
    if (i == 0) { rowstart[0] = 0; cursor[0] = 0; }
}

__global__ __launch_bounds__(256) void scatter_kernel(
        const int* __restrict__ ei, int* __restrict__ cursor, int* __restrict__ col) {
    int e = blockIdx.x * 256 + threadIdx.x;
    if (e >= E_TOT) return;
    int sv, dv;
    if (e < N_EDGES) { sv = ei[e]; dv = ei[N_EDGES + e]; }
    else             { sv = dv = e - N_EDGES; }
    int pos = atomicAdd(&cursor[dv], 1);
    col[pos] = sv;
}

// ====== Layer 1 MFMA GEMM + fused logits: h1b(bf16), al1, ar1 ===============
__global__ __launch_bounds__(256) void gemm1_mfma(
        const float* __restrict__ x, const ushort_t* __restrict__ W1f,
        const float* __restrict__ a_src, const float* __restrict__ a_dst,
        ushort_t* __restrict__ h1b, float* __restrict__ al, float* __restrict__ ar) {
    const int lane = threadIdx.x & 63;
    const int wv   = threadIdx.x >> 6;
    const int base = blockIdx.x * 64 + wv * 16;
    if (base >= N_NODES) return;
    const int am = base + (lane & 15);
    const int rm = am < N_NODES ? am : N_NODES - 1;

    bf16x8 a[4];
    const float* xr = &x[(size_t)rm * IN_CH + (lane >> 4) * 8];
    #pragma unroll
    for (int kk = 0; kk < 4; ++kk) {
        float4 lo = *(const float4*)&xr[kk * 32];
        float4 hi = *(const float4*)&xr[kk * 32 + 4];
        a[kk] = cvt8(lo, hi);
    }

    f32x4 acc[16];
    #pragma unroll
    for (int nt = 0; nt < 16; ++nt) acc[nt] = (f32x4){0.f, 0.f, 0.f, 0.f};

    const bf16x8* bp = (const bf16x8*)W1f;
    #pragma unroll
    for (int nt = 0; nt < 16; ++nt) {
        #pragma unroll
        for (int kk = 0; kk < 4; ++kk)
            acc[nt] = __builtin_amdgcn_mfma_f32_16x16x32_bf16(
                a[kk], bp[(nt * 4 + kk) * 64 + lane], acc[nt], 0, 0, 0);
    }

    #pragma unroll
    for (int r = 0; r < 4; ++r) {
        int node = base + (lane >> 4) * 4 + r;
        if (node < N_NODES) {
            unsigned* op = (unsigned*)&h1b[(size_t)node * HC + 2 * (lane & 15)];
            #pragma unroll
            for (int t = 0; t < 8; ++t)
                op[t * 16] = pack2(acc[2 * t][r], acc[2 * t + 1][r]);
        }
    }

    float asv[16], adv[16];
    #pragma unroll
    for (int nt = 0; nt < 16; ++nt) {
        int n = (nt >> 1) * 32 + 2 * (lane & 15) + (nt & 1);
        asv[nt] = a_src[n];
        adv[nt] = a_dst[n];
    }
    #pragma unroll
    for (int h = 0; h < HEADS; ++h) {
        #pragma unroll
        for (int r = 0; r < 4; ++r) {
            float s = acc[2 * h][r] * asv[2 * h] + acc[2 * h + 1][r] * asv[2 * h + 1];
            float d = acc[2 * h][r] * adv[2 * h] + acc[2 * h + 1][r] * adv[2 * h + 1];
            s += __shfl_xor(s, 1, 64); s += __shfl_xor(s, 2, 64);
            s += __shfl_xor(s, 4, 64); s += __shfl_xor(s, 8, 64);
            d += __shfl_xor(d, 1, 64); d += __shfl_xor(d, 2, 64);
            d += __shfl_xor(d, 4, 64); d += __shfl_xor(d, 8, 64);
            int node = base + (lane >> 4) * 4 + r;
            if ((lane & 15) == 0 && node < N_NODES) {
                al[node * HEADS + h] = s;
                ar[node * HEADS + h] = d;
            }
        }
    }
}

// ===== Layer 1 fused single-pass aggregation =================================
// Per 8-edge iteration: the 64 lanes compute the 8x8 (edge,head) exp matrix
// once; gather lanes receive exp and col via shuffle. Unnormalized accumulate,
// normalize by 1/denom at the end. No expv buffers, no second pass.
__global__ __launch_bounds__(256) void aggr1_csr(
        const int* __restrict__ rowstart, const int* __restrict__ col,
        const float* __restrict__ al, const float* __restrict__ ar,
        const unsigned short* __restrict__ h1b, const float* __restrict__ b1,
        unsigned short* __restrict__ out1b) {
    const int lane = threadIdx.x & 63;
    const int d = blockIdx.x * 4 + (threadIdx.x >> 6);
    if (d >= N_NODES) return;
    const int beg = rowstart[d], end = rowstart[d + 1];

    const int eq = lane >> 3;                    // my exp edge slot 0..7
    const int eh = lane & 7;                     // my exp head
    const float ar_eh = ar[d * HEADS + eh];
    const int half = lane >> 5;                  // gather: 0 = even, 1 = odd edges
    const int L    = lane & 31;                  // channel block c = L*8..L*8+7
    const int hh   = L >> 2;                     // head of my channels

    float dsum = 0.f;
    float acc8[8] = {0.f,0.f,0.f,0.f,0.f,0.f,0.f,0.f};

    for (int i = beg; i < end; i += 8) {
        const int e = i + eq;
        const int sv_e = col[e < end ? e : end - 1];
        const float ex = (e < end) ? lrexp(al[sv_e * HEADS + eh] + ar_eh) : 0.f;
        dsum += ex;
        #pragma unroll
        for (int q = 0; q < 4; ++q) {
            const int src = (2 * q + half) * 8;
            const int   sq = __shfl(sv_e, src, 64);        // col of edge i+2q+half
            const float wq = __shfl(ex, src + hh, 64);     // its exp for head hh (0 if OOB)
            const u16x8 v = *(const u16x8*)&h1b[(size_t)sq * HC + L * 8];
            #pragma unroll
            for (int j = 0; j < 8; ++j) acc8[j] += wq * bf2f(v[j]);
        }
    }
    // denominator: sum exp over edge slots (lanes sharing eh differ in bits 3..5)
    dsum += __shfl_xor(dsum, 8, 64);
    dsum += __shfl_xor(dsum, 16, 64);
    dsum += __shfl_xor(dsum, 32, 64);            // lane now holds denom[lane&7]
    const float inv = 1.f / (__shfl(dsum, hh, 64) + 1e-16f);
    #pragma unroll
    for (int j = 0; j < 8; ++j) acc8[j] *= inv;
    // combine even/odd halves
    #pragma unroll
    for (int j = 0; j < 8; ++j) acc8[j] += __shfl_xor(acc8[j], 32, 64);

    if (half == 0) {
        const float4 b0 = *(const float4*)&b1[L * 8];
        const float4 b4 = *(const float4*)&b1[L * 8 + 4];
        float bb[8] = {b0.x, b0.y, b0.z, b0.w, b4.x, b4.y, b4.z, b4.w};
        u16x8 ov;
        #pragma unroll
        for (int j = 0; j < 8; ++j) {
            float v = acc8[j] + bb[j];
            v = v > 0.f ? v : expf(v) - 1.f;
            ov[j] = f2bf(v);
        }
        *(u16x8*)&out1b[(size_t)d * HC + L * 8] = ov;
    }
}

// ====== Layer 2 MFMA GEMM + fused logits: h2b(bf16), al2, ar2 ===============
__global__ __launch_bounds__(256) void gemm2_mfma(
        const ushort_t* __restrict__ hinb, const ushort_t* __restrict__ W2f,
        const float* __restrict__ a_src, const float* __restrict__ a_dst,
        ushort_t* __restrict__ h2b, float* __restrict__ al, float* __restrict__ ar) {
    const int lane = threadIdx.x & 63;
    const int wv   = threadIdx.x >> 6;
    const int base = blockIdx.x * 64 + wv * 16;
    if (base >= N_NODES) return;
    const int am = base + (lane & 15);
    const int rm = am < N_NODES ? am : N_NODES - 1;

    bf16x8 a[8];
    const bf16x8* ap = (const bf16x8*)&hinb[(size_t)rm * HC];
    #pragma unroll
    for (int kk = 0; kk < 8; ++kk)
        a[kk] = ap[kk * 4 + (lane >> 4)];

    f32x4 acc[4];
    #pragma unroll
    for (int nt = 0; nt < 4; ++nt) acc[nt] = (f32x4){0.f, 0.f, 0.f, 0.f};

    const bf16x8* bp = (const bf16x8*)W2f;
    #pragma unroll
    for (int nt = 0; nt < 4; ++nt) {
        #pragma unroll
        for (int kk = 0; kk < 8; ++kk)
            acc[nt] = __builtin_amdgcn_mfma_f32_16x16x32_bf16(
                a[kk], bp[(nt * 8 + kk) * 64 + lane], acc[nt], 0, 0, 0);
    }

    #pragma unroll
    for (int r = 0; r < 4; ++r) {
        int node = base + (lane >> 4) * 4 + r;
        if (node < N_NODES) {
            unsigned* op = (unsigned*)&h2b[(size_t)node * OUTC + 2 * (lane & 15)];
            #pragma unroll
            for (int t = 0; t < 2; ++t)
                op[t * 16] = pack2(acc[2 * t][r], acc[2 * t + 1][r]);
        }
    }

    float asv[4], adv[4];
    #pragma unroll
    for (int nt = 0; nt < 4; ++nt) {
        int n = (nt >> 1) * 32 + 2 * (lane & 15) + (nt & 1);
        asv[nt] = a_src[n];
        adv[nt] = a_dst[n];
    }
    #pragma unroll
    for (int r = 0; r < 4; ++r) {
        float s = 0.f, d = 0.f;
        #pragma unroll
        for (int nt = 0; nt < 4; ++nt) {
            s += acc[nt][r] * asv[nt];
            d += acc[nt][r] * adv[nt];
        }
        s += __shfl_xor(s, 1, 64); s += __shfl_xor(s, 2, 64);
        s += __shfl_xor(s, 4, 64); s += __shfl_xor(s, 8, 64);
        d += __shfl_xor(d, 1, 64); d += __shfl_xor(d, 2, 64);
        d += __shfl_xor(d, 4, 64); d += __shfl_xor(d, 8, 64);
        int node = base + (lane >> 4) * 4 + r;
        if ((lane & 15) == 0 && node < N_NODES) { al[node] = s; ar[node] = d; }
    }
}

// ===== Layer 2 fused single-pass aggregation ================================
// 8 edges/iter: every lane computes exp of edge (lane&7); gather lanes get
// exp+col via shuffle. Unnormalized accumulate, normalize at end.
__global__ __launch_bounds__(256) void aggr2_csr(
        const int* __restrict__ rowstart, const int* __restrict__ col,
        const float* __restrict__ al, const float* __restrict__ ar,
        const unsigned short* __restrict__ h2b, const float* __restrict__ b2,
        float* __restrict__ out) {
    const int lane = threadIdx.x & 63;
    const int d = blockIdx.x * 4 + (threadIdx.x >> 6);
    if (d >= N_NODES) return;
    const int beg = rowstart[d], end = rowstart[d + 1];
    const float ard = ar[d];

    const int e8 = lane & 7;      // my exp edge slot (replicated across 8 groups)
    const int g  = lane >> 4;     // gather edge slot 0..3
    const int L  = lane & 15;     // channel block c = L*4..L*4+3

    float dsum = 0.f;
    float4 acc = {0.f, 0.f, 0.f, 0.f};

    for (int i = beg; i < end; i += 8) {
        const int e = i + e8;
        const int sv_e = col[e < end ? e : end - 1];
        const float ex = (e < end) ? lrexp(al[sv_e] + ard) : 0.f;
        dsum += ex;
        #pragma unroll
        for (int q = 0; q < 2; ++q) {
            const int slot = q * 4 + g;
            const int   sq = __shfl(sv_e, slot, 64);
            const float wq = __shfl(ex, slot, 64);
            const ushort4 v = *(const ushort4*)&h2b[(size_t)sq * OUTC + L * 4];
            acc.x += wq * bf2f(v.x); acc.y += wq * bf2f(v.y);
            acc.z += wq * bf2f(v.z); acc.w += wq * bf2f(v.w);
        }
    }
    // denominator: dsum identical across the 8 lane-groups; sum over e8 only
    dsum += __shfl_xor(dsum, 1, 64);
    dsum += __shfl_xor(dsum, 2, 64);
    dsum += __shfl_xor(dsum, 4, 64);
    const float inv = 1.f / (dsum + 1e-16f);
    acc.x *= inv; acc.y *= inv; acc.z *= inv; acc.w *= inv;
    // combine the 4 gather slots
    #pragma unroll
    for (int o = 16; o < 64; o <<= 1) {
        acc.x += __shfl_xor(acc.x, o, 64);
        acc.y += __shfl_xor(acc.y, o, 64);
        acc.z += __shfl_xor(acc.z, o, 64);
        acc.w += __shfl_xor(acc.w, o, 64);
    }
    if (g == 0) {
        const float4 bb = *(const float4*)&b2[L * 4];
        float4 ov = { acc.x + bb.x, acc.y + bb.y, acc.z + bb.z, acc.w + bb.w };
        *(float4*)&out[(size_t)d * OUTC + L * 4] = ov;
    }
}

extern "C" void kernel_launch(void* const* d_in, const int* in_sizes, int n_in,
                              void* d_out, int out_size, void* d_ws, size_t ws_size,
                              hipStream_t stream) {
    const float* x      = (const float*)d_in[0];
    const int*   ei     = (const int*)  d_in[1];
    const float* W1     = (const float*)d_in[2];
    const float* a_src1 = (const float*)d_in[3];
    const float* a_dst1 = (const float*)d_in[4];
    const float* b1     = (const float*)d_in[5];
    const float* W2     = (const float*)d_in[6];
    const float* a_src2 = (const float*)d_in[7];
    const float* a_dst2 = (const float*)d_in[8];
    const float* b2     = (const float*)d_in[9];
    float* out = (float*)d_out;

    // ---- workspace layout ----
    char* p = (char*)d_ws;
    ushort_t* h1b   = (ushort_t*)p; p += (size_t)N_NODES * HC * 2;   // 25.6 MB
    ushort_t* out1b = (ushort_t*)p; p += (size_t)N_NODES * HC * 2;   // 25.6 MB
    ushort_t* h2b   = (ushort_t*)p; p += (size_t)N_NODES * OUTC * 2; // 6.4 MB
    ushort_t* W1f  = (ushort_t*)p; p += 32768 * 2;                   // 64 KB
    ushort_t* W2f  = (ushort_t*)p; p += 16384 * 2;                   // 32 KB
    float* al1  = (float*)p;  p += (size_t)N_NODES * HEADS * sizeof(float);
    float* ar1  = (float*)p;  p += (size_t)N_NODES * HEADS * sizeof(float);
    float* al2  = (float*)p;  p += (size_t)N_NODES * sizeof(float);
    float* ar2  = (float*)p;  p += (size_t)N_NODES * sizeof(float);
    int* deg      = (int*)p;  p += (size_t)N_NODES * sizeof(int);
    int* inc      = (int*)p;  p += (size_t)N_NODES * sizeof(int);
    int* bsum     = (int*)p;  p += (size_t)NSCAN_BLOCKS * sizeof(int);
    int* rowstart = (int*)p;  p += (size_t)(N_NODES + 1) * sizeof(int);
    int* cursor   = (int*)p;  p += (size_t)N_NODES * sizeof(int);
    int* col      = (int*)p;  p += (size_t)E_TOT * sizeof(int);

    // ---- CSR build + weight repack (merged) ----
    hipMemsetAsync(deg, 0, (size_t)N_NODES * sizeof(int), stream);
    prep_kernel    <<<(E_TOT + 255)/256, 256, 0, stream>>>(ei, deg, W1, W2, W1f, W2f);
    scan1_kernel   <<<NSCAN_BLOCKS, 1024, 0, stream>>>(deg, inc, bsum);
    finalize_kernel<<<(N_NODES + 255)/256, 256, 0, stream>>>(inc, bsum, rowstart, cursor);
    scatter_kernel <<<(E_TOT + 255)/256, 256, 0, stream>>>(ei, cursor, col);

    // ---- layer 1 ----
    gemm1_mfma <<<(N_NODES + 63)/64, 256, 0, stream>>>(x, W1f, a_src1, a_dst1, h1b, al1, ar1);
    aggr1_csr  <<<(N_NODES + 3)/4, 256, 0, stream>>>(rowstart, col, al1, ar1, h1b, b1, out1b);

    // ---- layer 2 ----
    gemm2_mfma <<<(N_NODES + 63)/64, 256, 0, stream>>>(out1b, W2f, a_src2, a_dst2, h2b, al2, ar2);
    aggr2_csr  <<<(N_NODES + 3)/4, 256, 0, stream>>>(rowstart, col, al2, ar2, h2b, b2, out);
}